// Round 3
// baseline (3719.285 us; speedup 1.0000x reference)
//
#include <hip/hip_runtime.h>
#include <stdint.h>

#define BB 64
#define TT 128
#define INF 257
#define KP 288
#define HH 1024
#define G4 4096

typedef _Float16 half8 __attribute__((ext_vector_type(8)));
typedef float f4 __attribute__((ext_vector_type(4)));

__device__ __forceinline__ f4 mfma16(half8 a, half8 b, f4 c) {
  return __builtin_amdgcn_mfma_f32_16x16x32_f16(a, b, c, 0, 0, 0);
}

// async global->LDS, 16B per lane; LDS dest is wave-uniform base + lane*16
__device__ __forceinline__ void gld_lds16(const void* g, void* l) {
  auto gp = reinterpret_cast<__attribute__((address_space(1))) void*>(reinterpret_cast<uintptr_t>(g));
  auto lp = reinterpret_cast<__attribute__((address_space(3))) void*>(reinterpret_cast<uintptr_t>(l));
  __builtin_amdgcn_global_load_lds(gp, lp, 16, 0, 0);
}

// ---------- prep kernels ----------
__global__ __launch_bounds__(256) void k_cast_X(const float* __restrict__ X, _Float16* __restrict__ Xt) {
  int o = blockIdx.x * 256 + threadIdx.x;
  if (o >= TT * BB * KP) return;
  int k = o % KP, m = o / KP;
  int t = m >> 6, b = m & 63;
  float v = (k < INF) ? X[((size_t)b * TT + t) * INF + k] : 0.f;
  Xt[o] = (_Float16)v;
}

__global__ __launch_bounds__(256) void k_cast_padW(const float* __restrict__ W, _Float16* __restrict__ Wp) {
  int o = blockIdx.x * 256 + threadIdx.x;
  if (o >= G4 * KP) return;
  int k = o % KP, n = o / KP;
  Wp[o] = (_Float16)((k < INF) ? W[(size_t)n * INF + k] : 0.f);
}

__global__ __launch_bounds__(256) void k_cast(const float* __restrict__ W, _Float16* __restrict__ Wh, int n) {
  int o = blockIdx.x * 256 + threadIdx.x;
  if (o < n) Wh[o] = (_Float16)W[o];
}

__global__ __launch_bounds__(256) void k_bias(const float* __restrict__ a, const float* __restrict__ b,
                                              const float* __restrict__ c, const float* __restrict__ d,
                                              float* __restrict__ b0, float* __restrict__ b1) {
  int o = blockIdx.x * 256 + threadIdx.x;
  if (o < G4) { b0[o] = a[o] + b[o]; b1[o] = c[o] + d[o]; }
}

// ---------- big GEMM: C[M,4096] = A[M,K] @ Bw[N,K]^T + bias, fp16 out ----------
__global__ __launch_bounds__(256) void k_gemm(const _Float16* __restrict__ A, const _Float16* __restrict__ Bw,
                                              const float* __restrict__ bias, _Float16* __restrict__ C,
                                              int K, int lda, int ldb) {
  __shared__ __align__(16) _Float16 As[4 * 128 * 8];
  __shared__ __align__(16) _Float16 Bs[4 * 128 * 8];
  const int tid = threadIdx.x;
  const int w = tid >> 6, lane = tid & 63;
  const int q = lane >> 4, ml = lane & 15;
  const int m0 = blockIdx.x * 128, n0 = blockIdx.y * 128;
  const int wm = (w >> 1) * 64, wn = (w & 1) * 64;
  f4 acc[4][4] = {};
  const int kt_iters = K >> 5;
  for (int kt = 0; kt < kt_iters; ++kt) {
    __syncthreads();
#pragma unroll
    for (int i = 0; i < 2; ++i) {
      int cb = i * 256 + w * 64;
      int kc = cb >> 7, mb = cb & 127;
      gld_lds16(A + (size_t)(m0 + mb + lane) * lda + kt * 32 + kc * 8, (char*)As + (size_t)cb * 16);
      gld_lds16(Bw + (size_t)(n0 + mb + lane) * ldb + kt * 32 + kc * 8, (char*)Bs + (size_t)cb * 16);
    }
    __syncthreads();
    half8 af[4], bf[4];
#pragma unroll
    for (int tm = 0; tm < 4; ++tm) af[tm] = *(const half8*)(As + ((size_t)q * 128 + wm + tm * 16 + ml) * 8);
#pragma unroll
    for (int tn = 0; tn < 4; ++tn) bf[tn] = *(const half8*)(Bs + ((size_t)q * 128 + wn + tn * 16 + ml) * 8);
#pragma unroll
    for (int tm = 0; tm < 4; ++tm)
#pragma unroll
      for (int tn = 0; tn < 4; ++tn)
        acc[tm][tn] = mfma16(af[tm], bf[tn], acc[tm][tn]);
  }
#pragma unroll
  for (int tn = 0; tn < 4; ++tn) {
    int n = n0 + wn + tn * 16 + ml;
    float bv = bias[n];
#pragma unroll
    for (int tm = 0; tm < 4; ++tm) {
#pragma unroll
      for (int r = 0; r < 4; ++r) {
        int m = m0 + wm + tm * 16 + q * 4 + r;
        C[(size_t)m * G4 + n] = (_Float16)(acc[tm][tn][r] + bv);
      }
    }
  }
}

// ---------- persistent recurrence: one launch per layer, 128 steps inside ----------
// Grid 256 WGs (1/CU, co-resident) x 256 thr. WG (mg,ug): rows [mg*16..), units [ug*16..).
// Wave w = K-quarter. B frags (Whh slice, 128 VGPRs) loaded ONCE for all steps.
// c-state in a register per thread. Manual 2-level grid barrier per step in `bar`:
//   bar[g*16] g=0..7 group counters (padded), bar[128] level-2, bar[144] release flag.
__global__ __launch_bounds__(256, 1) void k_rec(const _Float16* __restrict__ xg,  // [T][64][4096]
                                                const _Float16* __restrict__ Whh, // [4096][1024]
                                                _Float16* __restrict__ y,         // [T][64][1024]
                                                unsigned* __restrict__ bar) {
  __shared__ __align__(16) _Float16 As[128 * 16 * 8];   // [k8][row][8] = 32 KB
  __shared__ float gl[4][4][16][16];                    // [kwave][gate][brow][unit]
  const int tid = threadIdx.x;
  const int w = tid >> 6, lane = tid & 63;
  const int q = lane >> 4, ml = lane & 15;
  const int ug = blockIdx.x & 63, mg = blockIdx.x >> 6;
  const int u0 = ug * 16, b0 = mg * 16;
  const int brow = tid >> 4, u = tid & 15;
  const int bi = b0 + brow, col = u0 + u;

  // B fragments once: col = tn*HH + u0 + ml (Whh row), k = w*256 + kt*32 + q*8
  half8 bf[4][8];
  {
    const _Float16* Bbase = Whh + (size_t)(u0 + ml) * HH + w * 256 + q * 8;
#pragma unroll
    for (int tn = 0; tn < 4; ++tn)
#pragma unroll
      for (int kt = 0; kt < 8; ++kt)
        bf[tn][kt] = *(const half8*)(Bbase + (size_t)tn * HH * HH + kt * 32);
  }

  unsigned* grp = bar + (blockIdx.x & 7) * 16;
  unsigned* cnt2 = bar + 128;
  unsigned* flag = bar + 144;
  float c_reg = 0.f;

  for (int t = 0; t < TT; ++t) {
    // xg loads for this step (independent of the barrier; L3-resident)
    const _Float16* xp = xg + ((size_t)t * BB + bi) * G4 + col;
    _Float16 xv0 = xp[0];
    _Float16 xv1 = xp[HH];
    _Float16 xv2 = xp[2 * HH];
    _Float16 xv3 = xp[3 * HH];

    f4 acc[4] = {};
    if (t > 0) {
      const _Float16* hprev = y + (size_t)(t - 1) * BB * HH;
#pragma unroll
      for (int j = 0; j < 8; ++j) {
        int ci = (w * 8 + j) * 64;   // chunk c = ci + lane -> row = lane&15, k8 = ci/16 + lane/16
        gld_lds16(hprev + (size_t)(b0 + ml) * HH + (size_t)(ci / 16 + q) * 8,
                  (char*)As + (size_t)ci * 16);
      }
      __syncthreads();  // staging drained (vmcnt0 per wave) + all waves past prev epilogue
#pragma unroll
      for (int kt = 0; kt < 8; ++kt) {
        half8 af = *(const half8*)(As + ((size_t)(w * 32 + kt * 4 + q) * 16 + ml) * 8);
#pragma unroll
        for (int tn = 0; tn < 4; ++tn)
          acc[tn] = mfma16(af, bf[tn][kt], acc[tn]);
      }
    }
    // K-partials to LDS; C/D layout: unit = ml, brow = q*4 + r
#pragma unroll
    for (int tn = 0; tn < 4; ++tn)
#pragma unroll
      for (int r = 0; r < 4; ++r)
        gl[w][tn][q * 4 + r][ml] = acc[tn][r];
    __syncthreads();

    float g0 = (float)xv0 + gl[0][0][brow][u] + gl[1][0][brow][u] + gl[2][0][brow][u] + gl[3][0][brow][u];
    float g1 = (float)xv1 + gl[0][1][brow][u] + gl[1][1][brow][u] + gl[2][1][brow][u] + gl[3][1][brow][u];
    float g2 = (float)xv2 + gl[0][2][brow][u] + gl[1][2][brow][u] + gl[2][2][brow][u] + gl[3][2][brow][u];
    float g3 = (float)xv3 + gl[0][3][brow][u] + gl[1][3][brow][u] + gl[2][3][brow][u] + gl[3][3][brow][u];
    float I = 1.f / (1.f + __expf(-g0));
    float F = 1.f / (1.f + __expf(-g1));
    float G = tanhf(g2);
    float O = 1.f / (1.f + __expf(-g3));
    c_reg = F * c_reg + I * G;
    y[((size_t)t * BB + bi) * HH + col] = (_Float16)(O * tanhf(c_reg));

    if (t + 1 < TT) {
      __syncthreads();  // all h-stores of this WG drained to L2 before rep fences
      if (tid == 0) {
        __threadfence();                                   // release: wb this XCD's L2
        unsigned o1 = atomicAdd(grp, 1u);
        if ((o1 & 31u) == 31u) {                           // last of 32 in group
          unsigned o2 = atomicAdd(cnt2, 1u);
          if ((o2 & 7u) == 7u)                             // last group
            __hip_atomic_store(flag, (unsigned)(t + 1), __ATOMIC_RELEASE,
                               __HIP_MEMORY_SCOPE_AGENT);
        }
        while (__hip_atomic_load(flag, __ATOMIC_RELAXED, __HIP_MEMORY_SCOPE_AGENT) <
               (unsigned)(t + 1))
          __builtin_amdgcn_s_sleep(2);
        __threadfence();                                   // acquire: inv L1/L2 (stale poison!)
      }
      __syncthreads();
    }
  }
}

// ---------- output head ----------
__global__ __launch_bounds__(256) void k_out(const _Float16* __restrict__ y2, const float* __restrict__ Wy,
                                             const float* __restrict__ by, float* __restrict__ out) {
  int gw = blockIdx.x * 4 + (threadIdx.x >> 6);
  int lane = threadIdx.x & 63;
  int t = gw >> 6, b = gw & 63;
  const _Float16* row = y2 + (size_t)gw * HH;
  float p0 = 0.f, p1 = 0.f;
#pragma unroll
  for (int i = 0; i < 16; ++i) {
    int k = i * 64 + lane;
    float v = tanhf((float)row[k]);
    p0 += v * Wy[k];
    p1 += v * Wy[HH + k];
  }
  for (int off = 32; off > 0; off >>= 1) {
    p0 += __shfl_down(p0, off);
    p1 += __shfl_down(p1, off);
  }
  if (lane == 0) {
    out[((size_t)b * TT + t) * 2 + 0] = p0 + by[0];
    out[((size_t)b * TT + t) * 2 + 1] = p1 + by[1];
  }
}

extern "C" void kernel_launch(void* const* d_in, const int* in_sizes, int n_in,
                              void* d_out, int out_size, void* d_ws, size_t ws_size,
                              hipStream_t stream) {
  (void)in_sizes; (void)n_in; (void)out_size; (void)ws_size;
  const float* X    = (const float*)d_in[0];
  const float* Wih0 = (const float*)d_in[3];
  const float* Whh0 = (const float*)d_in[4];
  const float* bih0 = (const float*)d_in[5];
  const float* bhh0 = (const float*)d_in[6];
  const float* Wih1 = (const float*)d_in[7];
  const float* Whh1 = (const float*)d_in[8];
  const float* bih1 = (const float*)d_in[9];
  const float* bhh1 = (const float*)d_in[10];
  const float* Wy   = (const float*)d_in[11];
  const float* by   = (const float*)d_in[12];
  float* out = (float*)d_out;

  char* p = (char*)d_ws;
  auto carve = [&](size_t bytes) { char* r = p; p += (bytes + 255) & ~(size_t)255; return r; };
  _Float16* Xt    = (_Float16*)carve((size_t)TT * BB * KP * 2);
  _Float16* W0p   = (_Float16*)carve((size_t)G4 * KP * 2);
  _Float16* Whh0h = (_Float16*)carve((size_t)G4 * HH * 2);
  _Float16* Wih1h = (_Float16*)carve((size_t)G4 * HH * 2);
  _Float16* Whh1h = (_Float16*)carve((size_t)G4 * HH * 2);
  float* b0 = (float*)carve((size_t)G4 * 4);
  float* b1 = (float*)carve((size_t)G4 * 4);
  _Float16* xg = (_Float16*)carve((size_t)TT * BB * G4 * 2);
  _Float16* y1 = (_Float16*)carve((size_t)TT * BB * HH * 2);
  _Float16* y2 = (_Float16*)carve((size_t)TT * BB * HH * 2);
  unsigned* bar0 = (unsigned*)carve(1024);
  unsigned* bar1 = (unsigned*)carve(1024);

  hipMemsetAsync(bar0, 0, 2048, stream);  // zero both barrier regions (ws is poisoned 0xAA)

  k_cast_X<<<(TT * BB * KP + 255) / 256, 256, 0, stream>>>(X, Xt);
  k_cast_padW<<<(G4 * KP + 255) / 256, 256, 0, stream>>>(Wih0, W0p);
  k_cast<<<(G4 * HH + 255) / 256, 256, 0, stream>>>(Whh0, Whh0h, G4 * HH);
  k_cast<<<(G4 * HH + 255) / 256, 256, 0, stream>>>(Wih1, Wih1h, G4 * HH);
  k_cast<<<(G4 * HH + 255) / 256, 256, 0, stream>>>(Whh1, Whh1h, G4 * HH);
  k_bias<<<(G4 + 255) / 256, 256, 0, stream>>>(bih0, bhh0, bih1, bhh1, b0, b1);

  // layer 0
  k_gemm<<<dim3(TT * BB / 128, G4 / 128), 256, 0, stream>>>(Xt, W0p, b0, xg, KP, KP, KP);
  k_rec<<<256, 256, 0, stream>>>(xg, Whh0h, y1, bar0);
  // layer 1
  k_gemm<<<dim3(TT * BB / 128, G4 / 128), 256, 0, stream>>>(y1, Wih1h, b1, xg, HH, HH, HH);
  k_rec<<<256, 256, 0, stream>>>(xg, Whh1h, y2, bar1);

  k_out<<<(TT * BB) / 4, 256, 0, stream>>>(y2, Wy, by, out);
}

// Round 4
// 1480.922 us; speedup vs baseline: 2.5115x; 2.5115x over previous
//
#include <hip/hip_runtime.h>
#include <stdint.h>

#define BB 64
#define TT 128
#define INF 257
#define KP 288
#define HH 1024
#define G4 4096

typedef _Float16 half8 __attribute__((ext_vector_type(8)));
typedef float f4 __attribute__((ext_vector_type(4)));

__device__ __forceinline__ f4 mfma16(half8 a, half8 b, f4 c) {
  return __builtin_amdgcn_mfma_f32_16x16x32_f16(a, b, c, 0, 0, 0);
}

// async global->LDS, 16B per lane; LDS dest is wave-uniform base + lane*16
__device__ __forceinline__ void gld_lds16(const void* g, void* l) {
  auto gp = reinterpret_cast<__attribute__((address_space(1))) void*>(reinterpret_cast<uintptr_t>(g));
  auto lp = reinterpret_cast<__attribute__((address_space(3))) void*>(reinterpret_cast<uintptr_t>(l));
  __builtin_amdgcn_global_load_lds(gp, lp, 16, 0, 0);
}

// ---------- prep kernels ----------
__global__ __launch_bounds__(256) void k_cast_X(const float* __restrict__ X, _Float16* __restrict__ Xt) {
  int o = blockIdx.x * 256 + threadIdx.x;
  if (o >= TT * BB * KP) return;
  int k = o % KP, m = o / KP;
  int t = m >> 6, b = m & 63;
  float v = (k < INF) ? X[((size_t)b * TT + t) * INF + k] : 0.f;
  Xt[o] = (_Float16)v;
}

__global__ __launch_bounds__(256) void k_cast_padW(const float* __restrict__ W, _Float16* __restrict__ Wp) {
  int o = blockIdx.x * 256 + threadIdx.x;
  if (o >= G4 * KP) return;
  int k = o % KP, n = o / KP;
  Wp[o] = (_Float16)((k < INF) ? W[(size_t)n * INF + k] : 0.f);
}

__global__ __launch_bounds__(256) void k_cast(const float* __restrict__ W, _Float16* __restrict__ Wh, int n) {
  int o = blockIdx.x * 256 + threadIdx.x;
  if (o < n) Wh[o] = (_Float16)W[o];
}

__global__ __launch_bounds__(256) void k_bias(const float* __restrict__ a, const float* __restrict__ b,
                                              const float* __restrict__ c, const float* __restrict__ d,
                                              float* __restrict__ b0, float* __restrict__ b1) {
  int o = blockIdx.x * 256 + threadIdx.x;
  if (o < G4) { b0[o] = a[o] + b[o]; b1[o] = c[o] + d[o]; }
}

// ---------- big GEMM: C[M,4096] = A[M,K] @ Bw[N,K]^T + bias, fp16 out ----------
__global__ __launch_bounds__(256) void k_gemm(const _Float16* __restrict__ A, const _Float16* __restrict__ Bw,
                                              const float* __restrict__ bias, _Float16* __restrict__ C,
                                              int K, int lda, int ldb) {
  __shared__ __align__(16) _Float16 As[4 * 128 * 8];
  __shared__ __align__(16) _Float16 Bs[4 * 128 * 8];
  const int tid = threadIdx.x;
  const int w = tid >> 6, lane = tid & 63;
  const int q = lane >> 4, ml = lane & 15;
  const int m0 = blockIdx.x * 128, n0 = blockIdx.y * 128;
  const int wm = (w >> 1) * 64, wn = (w & 1) * 64;
  f4 acc[4][4] = {};
  const int kt_iters = K >> 5;
  for (int kt = 0; kt < kt_iters; ++kt) {
    __syncthreads();
#pragma unroll
    for (int i = 0; i < 2; ++i) {
      int cb = i * 256 + w * 64;
      int kc = cb >> 7, mb = cb & 127;
      gld_lds16(A + (size_t)(m0 + mb + lane) * lda + kt * 32 + kc * 8, (char*)As + (size_t)cb * 16);
      gld_lds16(Bw + (size_t)(n0 + mb + lane) * ldb + kt * 32 + kc * 8, (char*)Bs + (size_t)cb * 16);
    }
    __syncthreads();
    half8 af[4], bf[4];
#pragma unroll
    for (int tm = 0; tm < 4; ++tm) af[tm] = *(const half8*)(As + ((size_t)q * 128 + wm + tm * 16 + ml) * 8);
#pragma unroll
    for (int tn = 0; tn < 4; ++tn) bf[tn] = *(const half8*)(Bs + ((size_t)q * 128 + wn + tn * 16 + ml) * 8);
#pragma unroll
    for (int tm = 0; tm < 4; ++tm)
#pragma unroll
      for (int tn = 0; tn < 4; ++tn)
        acc[tm][tn] = mfma16(af[tm], bf[tn], acc[tm][tn]);
  }
#pragma unroll
  for (int tn = 0; tn < 4; ++tn) {
    int n = n0 + wn + tn * 16 + ml;
    float bv = bias[n];
#pragma unroll
    for (int tm = 0; tm < 4; ++tm) {
#pragma unroll
      for (int r = 0; r < 4; ++r) {
        int m = m0 + wm + tm * 16 + q * 4 + r;
        C[(size_t)m * G4 + n] = (_Float16)(acc[tm][tn][r] + bv);
      }
    }
  }
}

// ---------- persistent recurrence v2: 256 WGs x 512 thr (8 waves), fence-free barrier ----------
// WG (mg,ug): batches [mg*16..+16), units [ug*16..+16) x 4 gates. Wave w = K-eighth (K=128).
// B frags bf[4][4] = 64 VGPRs, loaded ONCE (Whh/bar non-restrict => remat across barrier
// atomics is unsound => compiler must keep them live). A frags load direct global->VGPR.
// h-stores are agent-scope atomics (sc1, bypass non-coherent L2) => no fences needed.
__global__ __launch_bounds__(512, 2) void k_rec(const _Float16* __restrict__ xg,  // [T][64][4096]
                                                const _Float16* Whh,              // [4096][1024] NOT restrict
                                                _Float16* __restrict__ y,         // [T][64][1024]
                                                unsigned* bar) {                  // NOT restrict
  __shared__ float gl[8][4][16][16];  // [kwave][gate][brow][unit] = 32 KB
  const int tid = threadIdx.x;
  const int w = tid >> 6, lane = tid & 63;
  const int q = lane >> 4, ml = lane & 15;
  const int ug = blockIdx.x & 63, mg = blockIdx.x >> 6;
  const int u0 = ug * 16, b0 = mg * 16;
  const int brow = (tid >> 4) & 15, u = tid & 15;
  const int bi = b0 + brow, col = u0 + u;

  // B fragments once: row = tn*HH + u0 + ml (Whh gate-row), k = w*128 + kt*32 + q*8
  half8 bf[4][4];
#pragma unroll
  for (int tn = 0; tn < 4; ++tn)
#pragma unroll
    for (int kt = 0; kt < 4; ++kt)
      bf[tn][kt] = *(const half8*)(Whh + (size_t)(tn * HH + u0 + ml) * HH + w * 128 + kt * 32 + q * 8);

  unsigned* grp = bar + (blockIdx.x & 7) * 16;
  unsigned* cnt2 = bar + 128;
  unsigned* flag = bar + 144;
  float c_reg = 0.f;

  for (int t = 0; t < TT; ++t) {
    _Float16 xv0 = (_Float16)0.f, xv1 = xv0, xv2 = xv0, xv3 = xv0;
    if (tid < 256) {  // epilogue threads prefetch xg (overlaps MFMA phase)
      const _Float16* xp = xg + ((size_t)t * BB + bi) * G4 + col;
      xv0 = xp[0]; xv1 = xp[HH]; xv2 = xp[2 * HH]; xv3 = xp[3 * HH];
    }
    f4 acc[4] = {};
    if (t > 0) {
      const _Float16* hp = y + (size_t)(t - 1) * BB * HH + (size_t)(b0 + ml) * HH + w * 128 + q * 8;
      half8 af[4];
#pragma unroll
      for (int kt = 0; kt < 4; ++kt) af[kt] = *(const half8*)(hp + kt * 32);
#pragma unroll
      for (int kt = 0; kt < 4; ++kt)
#pragma unroll
        for (int tn = 0; tn < 4; ++tn)
          acc[tn] = mfma16(af[kt], bf[tn][kt], acc[tn]);
    }
    // K-partials to LDS; C/D layout: unit = ml, brow = q*4 + r
#pragma unroll
    for (int tn = 0; tn < 4; ++tn)
#pragma unroll
      for (int r = 0; r < 4; ++r)
        gl[w][tn][q * 4 + r][ml] = acc[tn][r];
    __syncthreads();

    if (tid < 256) {
      float g0 = (float)xv0, g1 = (float)xv1, g2 = (float)xv2, g3 = (float)xv3;
#pragma unroll
      for (int kw = 0; kw < 8; ++kw) {
        g0 += gl[kw][0][brow][u];
        g1 += gl[kw][1][brow][u];
        g2 += gl[kw][2][brow][u];
        g3 += gl[kw][3][brow][u];
      }
      float I = 1.f / (1.f + __expf(-g0));
      float F = 1.f / (1.f + __expf(-g1));
      float G = tanhf(g2);
      float O = 1.f / (1.f + __expf(-g3));
      c_reg = F * c_reg + I * G;
      unsigned hv = (unsigned)__builtin_bit_cast(unsigned short, (_Float16)(O * tanhf(c_reg)));
      unsigned other = (unsigned)__shfl_xor((int)hv, 1);
      if ((tid & 1) == 0) {  // pack cols (u, u+1) into one u32, agent-scope store (sc1)
        unsigned word = hv | (other << 16);
        __hip_atomic_store((unsigned*)(y + ((size_t)t * BB + bi) * HH + col), word,
                           __ATOMIC_RELAXED, __HIP_MEMORY_SCOPE_AGENT);
      }
    }
    if (t + 1 < TT) {
      __syncthreads();  // every wave drains vmcnt(0): all h-stores at coherence point
      if (tid == 0) {
        unsigned o1 = atomicAdd(grp, 1u);
        if ((o1 & 31u) == 31u) {
          unsigned o2 = atomicAdd(cnt2, 1u);
          if ((o2 & 7u) == 7u)
            __hip_atomic_store(flag, (unsigned)(t + 1), __ATOMIC_RELAXED,
                               __HIP_MEMORY_SCOPE_AGENT);
        }
        while (__hip_atomic_load(flag, __ATOMIC_RELAXED, __HIP_MEMORY_SCOPE_AGENT) <
               (unsigned)(t + 1))
          __builtin_amdgcn_s_sleep(2);
      }
      __syncthreads();
    }
  }
}

// ---------- output head ----------
__global__ __launch_bounds__(256) void k_out(const _Float16* __restrict__ y2, const float* __restrict__ Wy,
                                             const float* __restrict__ by, float* __restrict__ out) {
  int gw = blockIdx.x * 4 + (threadIdx.x >> 6);
  int lane = threadIdx.x & 63;
  int t = gw >> 6, b = gw & 63;
  const _Float16* row = y2 + (size_t)gw * HH;
  float p0 = 0.f, p1 = 0.f;
#pragma unroll
  for (int i = 0; i < 16; ++i) {
    int k = i * 64 + lane;
    float v = tanhf((float)row[k]);
    p0 += v * Wy[k];
    p1 += v * Wy[HH + k];
  }
  for (int off = 32; off > 0; off >>= 1) {
    p0 += __shfl_down(p0, off);
    p1 += __shfl_down(p1, off);
  }
  if (lane == 0) {
    out[((size_t)b * TT + t) * 2 + 0] = p0 + by[0];
    out[((size_t)b * TT + t) * 2 + 1] = p1 + by[1];
  }
}

extern "C" void kernel_launch(void* const* d_in, const int* in_sizes, int n_in,
                              void* d_out, int out_size, void* d_ws, size_t ws_size,
                              hipStream_t stream) {
  (void)in_sizes; (void)n_in; (void)out_size; (void)ws_size;
  const float* X    = (const float*)d_in[0];
  const float* Wih0 = (const float*)d_in[3];
  const float* Whh0 = (const float*)d_in[4];
  const float* bih0 = (const float*)d_in[5];
  const float* bhh0 = (const float*)d_in[6];
  const float* Wih1 = (const float*)d_in[7];
  const float* Whh1 = (const float*)d_in[8];
  const float* bih1 = (const float*)d_in[9];
  const float* bhh1 = (const float*)d_in[10];
  const float* Wy   = (const float*)d_in[11];
  const float* by   = (const float*)d_in[12];
  float* out = (float*)d_out;

  char* p = (char*)d_ws;
  auto carve = [&](size_t bytes) { char* r = p; p += (bytes + 255) & ~(size_t)255; return r; };
  _Float16* Xt    = (_Float16*)carve((size_t)TT * BB * KP * 2);
  _Float16* W0p   = (_Float16*)carve((size_t)G4 * KP * 2);
  _Float16* Whh0h = (_Float16*)carve((size_t)G4 * HH * 2);
  _Float16* Wih1h = (_Float16*)carve((size_t)G4 * HH * 2);
  _Float16* Whh1h = (_Float16*)carve((size_t)G4 * HH * 2);
  float* b0 = (float*)carve((size_t)G4 * 4);
  float* b1 = (float*)carve((size_t)G4 * 4);
  _Float16* xg = (_Float16*)carve((size_t)TT * BB * G4 * 2);
  _Float16* y1 = (_Float16*)carve((size_t)TT * BB * HH * 2);
  _Float16* y2 = (_Float16*)carve((size_t)TT * BB * HH * 2);
  unsigned* bar0 = (unsigned*)carve(1024);
  unsigned* bar1 = (unsigned*)carve(1024);

  hipMemsetAsync(bar0, 0, 2048, stream);  // zero both barrier regions (ws is poisoned 0xAA)

  k_cast_X<<<(TT * BB * KP + 255) / 256, 256, 0, stream>>>(X, Xt);
  k_cast_padW<<<(G4 * KP + 255) / 256, 256, 0, stream>>>(Wih0, W0p);
  k_cast<<<(G4 * HH + 255) / 256, 256, 0, stream>>>(Whh0, Whh0h, G4 * HH);
  k_cast<<<(G4 * HH + 255) / 256, 256, 0, stream>>>(Wih1, Wih1h, G4 * HH);
  k_cast<<<(G4 * HH + 255) / 256, 256, 0, stream>>>(Whh1, Whh1h, G4 * HH);
  k_bias<<<(G4 + 255) / 256, 256, 0, stream>>>(bih0, bhh0, bih1, bhh1, b0, b1);

  // layer 0
  k_gemm<<<dim3(TT * BB / 128, G4 / 128), 256, 0, stream>>>(Xt, W0p, b0, xg, KP, KP, KP);
  k_rec<<<256, 512, 0, stream>>>(xg, Whh0h, y1, bar0);
  // layer 1
  k_gemm<<<dim3(TT * BB / 128, G4 / 128), 256, 0, stream>>>(y1, Wih1h, b1, xg, HH, HH, HH);
  k_rec<<<256, 512, 0, stream>>>(xg, Whh1h, y2, bar1);

  k_out<<<(TT * BB) / 4, 256, 0, stream>>>(y2, Wy, by, out);
}

// Round 6
// 1294.919 us; speedup vs baseline: 2.8722x; 1.1436x over previous
//
#include <hip/hip_runtime.h>
#include <stdint.h>

#define BB 64
#define TT 128
#define INF 257
#define KP 288
#define HH 1024
#define G4 4096

typedef _Float16 half8 __attribute__((ext_vector_type(8)));
typedef float f4 __attribute__((ext_vector_type(4)));

__device__ __forceinline__ f4 mfma16(half8 a, half8 b, f4 c) {
  return __builtin_amdgcn_mfma_f32_16x16x32_f16(a, b, c, 0, 0, 0);
}

// async global->LDS, 16B per lane; LDS dest is wave-uniform base + lane*16
__device__ __forceinline__ void gld_lds16(const void* g, void* l) {
  auto gp = reinterpret_cast<__attribute__((address_space(1))) void*>(reinterpret_cast<uintptr_t>(g));
  auto lp = reinterpret_cast<__attribute__((address_space(3))) void*>(reinterpret_cast<uintptr_t>(l));
  __builtin_amdgcn_global_load_lds(gp, lp, 16, 0, 0);
}

// ---------- prep kernels ----------
__global__ __launch_bounds__(256) void k_cast_X(const float* __restrict__ X, _Float16* __restrict__ Xt) {
  int o = blockIdx.x * 256 + threadIdx.x;
  if (o >= TT * BB * KP) return;
  int k = o % KP, m = o / KP;
  int t = m >> 6, b = m & 63;
  float v = (k < INF) ? X[((size_t)b * TT + t) * INF + k] : 0.f;
  Xt[o] = (_Float16)v;
}

__global__ __launch_bounds__(256) void k_cast_padW(const float* __restrict__ W, _Float16* __restrict__ Wp) {
  int o = blockIdx.x * 256 + threadIdx.x;
  if (o >= G4 * KP) return;
  int k = o % KP, n = o / KP;
  Wp[o] = (_Float16)((k < INF) ? W[(size_t)n * INF + k] : 0.f);
}

__global__ __launch_bounds__(256) void k_cast(const float* __restrict__ W, _Float16* __restrict__ Wh, int n) {
  int o = blockIdx.x * 256 + threadIdx.x;
  if (o < n) Wh[o] = (_Float16)W[o];
}

__global__ __launch_bounds__(256) void k_bias(const float* __restrict__ a, const float* __restrict__ b,
                                              const float* __restrict__ c, const float* __restrict__ d,
                                              float* __restrict__ b0, float* __restrict__ b1) {
  int o = blockIdx.x * 256 + threadIdx.x;
  if (o < G4) { b0[o] = a[o] + b[o]; b1[o] = c[o] + d[o]; }
}

// ---------- big GEMM: C[M,4096] = A[M,K] @ Bw[N,K]^T + bias, fp16 out ----------
__global__ __launch_bounds__(256) void k_gemm(const _Float16* __restrict__ A, const _Float16* __restrict__ Bw,
                                              const float* __restrict__ bias, _Float16* __restrict__ C,
                                              int K, int lda, int ldb) {
  __shared__ __align__(16) _Float16 As[4 * 128 * 8];
  __shared__ __align__(16) _Float16 Bs[4 * 128 * 8];
  const int tid = threadIdx.x;
  const int w = tid >> 6, lane = tid & 63;
  const int q = lane >> 4, ml = lane & 15;
  const int m0 = blockIdx.x * 128, n0 = blockIdx.y * 128;
  const int wm = (w >> 1) * 64, wn = (w & 1) * 64;
  f4 acc[4][4] = {};
  const int kt_iters = K >> 5;
  for (int kt = 0; kt < kt_iters; ++kt) {
    __syncthreads();
#pragma unroll
    for (int i = 0; i < 2; ++i) {
      int cb = i * 256 + w * 64;
      int kc = cb >> 7, mb = cb & 127;
      gld_lds16(A + (size_t)(m0 + mb + lane) * lda + kt * 32 + kc * 8, (char*)As + (size_t)cb * 16);
      gld_lds16(Bw + (size_t)(n0 + mb + lane) * ldb + kt * 32 + kc * 8, (char*)Bs + (size_t)cb * 16);
    }
    __syncthreads();
    half8 af[4], bf[4];
#pragma unroll
    for (int tm = 0; tm < 4; ++tm) af[tm] = *(const half8*)(As + ((size_t)q * 128 + wm + tm * 16 + ml) * 8);
#pragma unroll
    for (int tn = 0; tn < 4; ++tn) bf[tn] = *(const half8*)(Bs + ((size_t)q * 128 + wn + tn * 16 + ml) * 8);
#pragma unroll
    for (int tm = 0; tm < 4; ++tm)
#pragma unroll
      for (int tn = 0; tn < 4; ++tn)
        acc[tm][tn] = mfma16(af[tm], bf[tn], acc[tm][tn]);
  }
#pragma unroll
  for (int tn = 0; tn < 4; ++tn) {
    int n = n0 + wn + tn * 16 + ml;
    float bv = bias[n];
#pragma unroll
    for (int tm = 0; tm < 4; ++tm) {
#pragma unroll
      for (int r = 0; r < 4; ++r) {
        int m = m0 + wm + tm * 16 + q * 4 + r;
        C[(size_t)m * G4 + n] = (_Float16)(acc[tm][tn][r] + bv);
      }
    }
  }
}

// ---------- persistent recurrence v4: fine-grained counters + SOUND release ----------
// 256 WGs x 512 thr. WG (mg,ug): rows [mg*16..+16), units [ug*16..+16) x 4 gates.
// Wave w = K-eighth. h-store is __hip_atomic_exchange (returning atomic): executes AT the
// coherence point, vmcnt retires on value return => "exchange done" == "h visible at IC"
// by architecture (R5's fire-and-forget sc1 store raced: bump could beat the store to IC).
// Then s_waitcnt(0) + __syncthreads + one bump per WG. Consumer: per-(mg,kslice) wave spins.
__global__ __launch_bounds__(512, 2) void k_rec(const _Float16* __restrict__ xg,  // [T][64][4096]
                                                const _Float16* Whh,              // [4096][1024] NOT restrict
                                                _Float16* __restrict__ y,         // [T][64][1024]
                                                unsigned* bar) {                  // NOT restrict
  __shared__ float gl[8][4][16][16];  // [kwave][gate][brow][unit] = 32 KB
  const int tid = threadIdx.x;
  const int w = tid >> 6, lane = tid & 63;
  const int q = lane >> 4, ml = lane & 15;
  const int ug = blockIdx.x & 63, mg = blockIdx.x >> 6;
  const int u0 = ug * 16, b0 = mg * 16;
  const int brow = (tid >> 4) & 15, u = tid & 15;
  const int bi = b0 + brow, col = u0 + u;

  // B fragments once: row = tn*HH + u0 + ml (Whh gate-row), k = w*128 + kt*32 + q*8
  half8 bf[4][4];
#pragma unroll
  for (int tn = 0; tn < 4; ++tn)
#pragma unroll
    for (int kt = 0; kt < 4; ++kt)
      bf[tn][kt] = *(const half8*)(Whh + (size_t)(tn * HH + u0 + ml) * HH + w * 128 + kt * 32 + q * 8);

  unsigned* myArr = bar + (size_t)(mg * 8 + (ug >> 3)) * 64;  // counter this WG bumps
  unsigned* mySpin = bar + (size_t)(mg * 8 + w) * 64;         // counter wave w spins on
  float c_reg = 0.f;

  for (int t = 0; t < TT; ++t) {
    _Float16 xv0 = (_Float16)0.f, xv1 = xv0, xv2 = xv0, xv3 = xv0;
    if (tid < 256) {  // xg prefetch, in flight during the spin
      const _Float16* xp = xg + ((size_t)t * BB + bi) * G4 + col;
      xv0 = xp[0]; xv1 = xp[HH]; xv2 = xp[2 * HH]; xv3 = xp[3 * HH];
    }
    f4 acc[4] = {};
    if (t > 0) {
      if (lane == 0) {  // wave-level spin: my 8 producers done with step t-1 (at IC)
        unsigned tgt = 8u * (unsigned)t;
        while (__hip_atomic_load(mySpin, __ATOMIC_RELAXED, __HIP_MEMORY_SCOPE_AGENT) < tgt)
          __builtin_amdgcn_s_sleep(1);
      }
      asm volatile("" ::: "memory");  // order h loads after the spin
      const _Float16* hp = y + (size_t)(t - 1) * BB * HH + (size_t)(b0 + ml) * HH + w * 128 + q * 8;
      half8 af[4];
#pragma unroll
      for (int kt = 0; kt < 4; ++kt) af[kt] = *(const half8*)(hp + kt * 32);
#pragma unroll
      for (int kt = 0; kt < 4; ++kt)
#pragma unroll
        for (int tn = 0; tn < 4; ++tn)
          acc[tn] = mfma16(af[kt], bf[tn][kt], acc[tn]);
    }
    // K-partials to LDS; C/D layout: unit = ml, brow = q*4 + r
#pragma unroll
    for (int tn = 0; tn < 4; ++tn)
#pragma unroll
      for (int r = 0; r < 4; ++r)
        gl[w][tn][q * 4 + r][ml] = acc[tn][r];
    __syncthreads();

    if (tid < 256) {
      float g0 = (float)xv0, g1 = (float)xv1, g2 = (float)xv2, g3 = (float)xv3;
#pragma unroll
      for (int kw = 0; kw < 8; ++kw) {
        g0 += gl[kw][0][brow][u];
        g1 += gl[kw][1][brow][u];
        g2 += gl[kw][2][brow][u];
        g3 += gl[kw][3][brow][u];
      }
      float I = 1.f / (1.f + __expf(-g0));
      float F = 1.f / (1.f + __expf(-g1));
      float G = tanhf(g2);
      float O = 1.f / (1.f + __expf(-g3));
      c_reg = F * c_reg + I * G;
      unsigned hv = (unsigned)__builtin_bit_cast(unsigned short, (_Float16)(O * tanhf(c_reg)));
      unsigned other = (unsigned)__shfl_xor((int)hv, 1);
      if ((tid & 1) == 0) {  // pack cols (u, u+1): RETURNING atomic => executes at IC
        unsigned word = hv | (other << 16);
        (void)__hip_atomic_exchange((unsigned*)(y + ((size_t)t * BB + bi) * HH + col), word,
                                    __ATOMIC_RELAXED, __HIP_MEMORY_SCOPE_AGENT);
      }
    }
    if (t + 1 < TT) {
      __builtin_amdgcn_s_waitcnt(0);  // per-wave: exchange acks returned => h at IC
      __syncthreads();                // whole WG's h at IC
      if (tid == 0) atomicAdd(myArr, 1u);  // one arrival per WG per step, strictly after
    }
  }
}

// ---------- output head ----------
__global__ __launch_bounds__(256) void k_out(const _Float16* __restrict__ y2, const float* __restrict__ Wy,
                                             const float* __restrict__ by, float* __restrict__ out) {
  int gw = blockIdx.x * 4 + (threadIdx.x >> 6);
  int lane = threadIdx.x & 63;
  int t = gw >> 6, b = gw & 63;
  const _Float16* row = y2 + (size_t)gw * HH;
  float p0 = 0.f, p1 = 0.f;
#pragma unroll
  for (int i = 0; i < 16; ++i) {
    int k = i * 64 + lane;
    float v = tanhf((float)row[k]);
    p0 += v * Wy[k];
    p1 += v * Wy[HH + k];
  }
  for (int off = 32; off > 0; off >>= 1) {
    p0 += __shfl_down(p0, off);
    p1 += __shfl_down(p1, off);
  }
  if (lane == 0) {
    out[((size_t)b * TT + t) * 2 + 0] = p0 + by[0];
    out[((size_t)b * TT + t) * 2 + 1] = p1 + by[1];
  }
}

extern "C" void kernel_launch(void* const* d_in, const int* in_sizes, int n_in,
                              void* d_out, int out_size, void* d_ws, size_t ws_size,
                              hipStream_t stream) {
  (void)in_sizes; (void)n_in; (void)out_size; (void)ws_size;
  const float* X    = (const float*)d_in[0];
  const float* Wih0 = (const float*)d_in[3];
  const float* Whh0 = (const float*)d_in[4];
  const float* bih0 = (const float*)d_in[5];
  const float* bhh0 = (const float*)d_in[6];
  const float* Wih1 = (const float*)d_in[7];
  const float* Whh1 = (const float*)d_in[8];
  const float* bih1 = (const float*)d_in[9];
  const float* bhh1 = (const float*)d_in[10];
  const float* Wy   = (const float*)d_in[11];
  const float* by   = (const float*)d_in[12];
  float* out = (float*)d_out;

  char* p = (char*)d_ws;
  auto carve = [&](size_t bytes) { char* r = p; p += (bytes + 255) & ~(size_t)255; return r; };
  _Float16* Xt    = (_Float16*)carve((size_t)TT * BB * KP * 2);
  _Float16* W0p   = (_Float16*)carve((size_t)G4 * KP * 2);
  _Float16* Whh0h = (_Float16*)carve((size_t)G4 * HH * 2);
  _Float16* Wih1h = (_Float16*)carve((size_t)G4 * HH * 2);
  _Float16* Whh1h = (_Float16*)carve((size_t)G4 * HH * 2);
  float* b0 = (float*)carve((size_t)G4 * 4);
  float* b1 = (float*)carve((size_t)G4 * 4);
  _Float16* xg = (_Float16*)carve((size_t)TT * BB * G4 * 2);
  _Float16* y1 = (_Float16*)carve((size_t)TT * BB * HH * 2);
  _Float16* y2 = (_Float16*)carve((size_t)TT * BB * HH * 2);
  unsigned* bar0 = (unsigned*)carve(8192);   // 32 counters x 256 B
  unsigned* bar1 = (unsigned*)carve(8192);

  hipMemsetAsync(bar0, 0, 16384, stream);  // zero both barrier regions (ws is poisoned 0xAA)

  k_cast_X<<<(TT * BB * KP + 255) / 256, 256, 0, stream>>>(X, Xt);
  k_cast_padW<<<(G4 * KP + 255) / 256, 256, 0, stream>>>(Wih0, W0p);
  k_cast<<<(G4 * HH + 255) / 256, 256, 0, stream>>>(Whh0, Whh0h, G4 * HH);
  k_cast<<<(G4 * HH + 255) / 256, 256, 0, stream>>>(Wih1, Wih1h, G4 * HH);
  k_cast<<<(G4 * HH + 255) / 256, 256, 0, stream>>>(Whh1, Whh1h, G4 * HH);
  k_bias<<<(G4 + 255) / 256, 256, 0, stream>>>(bih0, bhh0, bih1, bhh1, b0, b1);

  // layer 0
  k_gemm<<<dim3(TT * BB / 128, G4 / 128), 256, 0, stream>>>(Xt, W0p, b0, xg, KP, KP, KP);
  k_rec<<<256, 512, 0, stream>>>(xg, Whh0h, y1, bar0);
  // layer 1
  k_gemm<<<dim3(TT * BB / 128, G4 / 128), 256, 0, stream>>>(y1, Wih1h, b1, xg, HH, HH, HH);
  k_rec<<<256, 512, 0, stream>>>(xg, Whh1h, y2, bar1);

  k_out<<<(TT * BB) / 4, 256, 0, stream>>>(y2, Wy, by, out);
}